// Round 8
// baseline (194.513 us; speedup 1.0000x reference)
//
#include <hip/hip_runtime.h>
#include <hip/hip_bf16.h>

typedef __bf16 bf16;
typedef bf16 bf16x8 __attribute__((ext_vector_type(8)));
typedef bf16 bf16x4 __attribute__((ext_vector_type(4)));
typedef float f32x4 __attribute__((ext_vector_type(4)));

#define Bn 8
#define Cdim 256
#define Nn 2304
#define NH 4
#define DH 32
#define HID 128
#define QSCALE (0.17677669529663687f * 1.4426950408889634f)
#define SMAX 14.0f
#define QSZ ((size_t)32 * Nn * DH)
#define WQ_ELEMS (3 * HID * Cdim)
#define WO_ELEMS (Cdim * HID)

// ---------------- Kernel 0: weight cvt + FRAG-MAJOR repack (gather) ----------
__global__ __launch_bounds__(256) void cvt_kernel(const float* __restrict__ wq,
                                                  const float* __restrict__ wo,
                                                  bf16* __restrict__ dst) {
    int d = blockIdx.x * 256 + threadIdx.x;
    {   // wq: 24 o-tiles, 8 kc
        int j = d & 7, lane = (d >> 3) & 63, kc = (d >> 9) & 7, ot = d >> 12;
        int o = ot * 16 + (lane & 15), c = kc * 32 + (lane >> 4) * 8 + j;
        dst[d] = (bf16)wq[o * Cdim + c];
    }
    if (d < WO_ELEMS) {   // wo: 16 o-tiles, 4 kc
        int j = d & 7, lane = (d >> 3) & 63, kc = (d >> 9) & 3, ot = d >> 11;
        int o = ot * 16 + (lane & 15), c = kc * 32 + (lane >> 4) * 8 + j;
        dst[WQ_ELEMS + d] = (bf16)wo[o * HID + c];
    }
}

// ---------------- Kernel 1: QKV projection (z-split x8) ----------------------
// Q stored [bh][n][32]; K stored FRAG-MAJOR; V stored TRANSPOSED [bh][32][n].
__global__ __launch_bounds__(256) void qkv_kernel(const float* __restrict__ x,
                                                  const bf16* __restrict__ w,
                                                  bf16* __restrict__ ws) {
    __shared__ bf16 xt[256 * 66];
    const int p0  = blockIdx.x * 64;
    const int b   = blockIdx.y;
    const int otb = blockIdx.z * 3;
    const int tid = threadIdx.x;
    const float* xb = x + (size_t)b * Cdim * Nn;

    {   const int pg = (tid & 15) * 4;
        const int c0 = tid >> 4;
        #pragma unroll
        for (int cc = 0; cc < 16; ++cc) {
            const int c = c0 + cc * 16;
            float4 v = *(const float4*)&xb[(size_t)c * Nn + p0 + pg];
            bf16x4 b4 = {(bf16)v.x, (bf16)v.y, (bf16)v.z, (bf16)v.w};
            *(bf16x4*)&xt[c * 66 + pg] = b4;
        }
    }
    __syncthreads();

    const int lane = tid & 63;
    const int w4   = tid >> 6;
    const int l16  = lane & 15;
    const int quad = lane >> 4;

    bf16x8 bx[8];
    #pragma unroll
    for (int kc = 0; kc < 8; ++kc)
        #pragma unroll
        for (int jj = 0; jj < 8; ++jj)
            bx[kc][jj] = xt[(kc * 32 + quad * 8 + jj) * 66 + w4 * 16 + l16];

    const int p = p0 + w4 * 16 + l16;
    #pragma unroll 1
    for (int oi = 0; oi < 3; ++oi) {
        const int ot = otb + oi;
        f32x4 acc0 = {0.f, 0.f, 0.f, 0.f};
        f32x4 acc1 = {0.f, 0.f, 0.f, 0.f};
        #pragma unroll
        for (int kc = 0; kc < 4; ++kc) {
            bf16x8 aw0 = *(const bf16x8*)&w[(((size_t)ot * 8 + kc) * 64 + lane) * 8];
            bf16x8 aw1 = *(const bf16x8*)&w[(((size_t)ot * 8 + kc + 4) * 64 + lane) * 8];
            acc0 = __builtin_amdgcn_mfma_f32_16x16x32_bf16(aw0, bx[kc],     acc0, 0, 0, 0);
            acc1 = __builtin_amdgcn_mfma_f32_16x16x32_bf16(aw1, bx[kc + 4], acc1, 0, 0, 0);
        }
        const int obase = ot * 16 + quad * 4;
        const int t     = obase >> 7;
        const int rem   = obase & 127;
        const int h     = rem >> 5;
        const int dbase = rem & 31;
        if (t == 2) {
            bf16* vt = ws + 2 * QSZ + (size_t)(b * NH + h) * DH * Nn;
            #pragma unroll
            for (int r = 0; r < 4; ++r)
                vt[(size_t)(dbase + r) * Nn + p] = (bf16)(acc0[r] + acc1[r]);
        } else if (t == 1) {
            bf16x4 v4;
            #pragma unroll
            for (int r = 0; r < 4; ++r) v4[r] = (bf16)(acc0[r] + acc1[r]);
            bf16* kf = ws + QSZ + (size_t)(b * NH + h) * Nn * DH;
            const int addr = ((p >> 4) * 64 + (dbase >> 3) * 16 + (p & 15)) * 8 + (dbase & 7);
            *(bf16x4*)&kf[addr] = v4;
        } else {
            bf16x4 v4;
            #pragma unroll
            for (int r = 0; r < 4; ++r) v4[r] = (bf16)((acc0[r] + acc1[r]) * QSCALE);
            size_t addr = ((size_t)(b * NH + h) * Nn + p) * DH + dbase;
            *(bf16x4*)&ws[addr] = v4;
        }
    }
}

// ---------------- Kernel 2: flash attention (8 waves/EU, single P buffer) ----
// XCD-pinned (g&7), in-WG split-K (wave = 576-j quarter of 16 Q-rows).
// Single 2KB P buffer per wave: loop order back(c); front(c+1) makes the
// write-after-read safe via the per-wave in-order DS pipe. LDS = 8.7KB/WG.
__global__ __launch_bounds__(256, 8) void attn_kernel(bf16* __restrict__ ws) {
    __shared__ alignas(16) char smem[8704];    // plds 8KB (main) / ob+l (tail)
    bf16* plds = (bf16*)smem;
    const int g   = blockIdx.x;
    const int grp = g >> 3;
    const int bh  = (g & 7) * 4 + grp / 144;
    const int it  = grp % 144;
    const int tid = threadIdx.x;
    const int lane = tid & 63, w4 = tid >> 6, l16 = lane & 15, quad = lane >> 4;
    const int i0 = it * 16;
    const int jbase = w4 * 576;

    const bf16* Qb = ws + (size_t)bh * Nn * DH;
    const bf16* Kf = ws + QSZ + (size_t)bh * Nn * DH;       // frag-major
    const bf16* Vt = ws + 2 * QSZ + (size_t)bh * DH * Nn;

    const bf16x8 aq = *(const bf16x8*)&Qb[(size_t)(i0 + l16) * DH + quad * 8];

    f32x4 o0 = {0.f,0.f,0.f,0.f}, o1 = {0.f,0.f,0.f,0.f}, lacc = {0.f,0.f,0.f,0.f};
    const f32x4 negM = {-SMAX, -SMAX, -SMAX, -SMAX};
    bf16x8 ones;
    #pragma unroll
    for (int j = 0; j < 8; ++j) ones[j] = (bf16)1.0f;

    const int swz = (l16 & 7) << 1;
    int wa[4];
    #pragma unroll
    for (int jt = 0; jt < 4; ++jt)
        wa[jt] = l16 * 64 + (((jt * 4) | quad) ^ swz) * 4;
    const int ra0 = l16 * 64 + ((quad * 2) ^ swz) * 4;
    const int ra1 = l16 * 64 + ((8 | (quad * 2)) ^ swz) * 4;

    bf16* pb = plds + w4 * 1024;

    auto loadK = [&](int j0, bf16x8* bk) {
        const bf16* kp = &Kf[(size_t)(j0 >> 4) * 512 + lane * 8];
        #pragma unroll
        for (int jt = 0; jt < 4; ++jt)
            bk[jt] = *(const bf16x8*)&kp[jt * 512];   // coalesced 1KB/instr
    };
    auto front = [&](const bf16x8* bk, int j0, bf16x8* bv) {
        const bf16* vp = &Vt[j0];
        bv[0] = *(const bf16x8*)&vp[(size_t)l16 * Nn + quad * 8];
        bv[1] = *(const bf16x8*)&vp[(size_t)l16 * Nn + 32 + quad * 8];
        bv[2] = *(const bf16x8*)&vp[(size_t)(l16 + 16) * Nn + quad * 8];
        bv[3] = *(const bf16x8*)&vp[(size_t)(l16 + 16) * Nn + 32 + quad * 8];
        #pragma unroll
        for (int jt = 0; jt < 4; ++jt) {
            f32x4 st = __builtin_amdgcn_mfma_f32_16x16x32_bf16(bk[jt], aq, negM, 0, 0, 0);
            bf16x4 pv4;
            #pragma unroll
            for (int r = 0; r < 4; ++r)
                pv4[r] = (bf16)__builtin_amdgcn_exp2f(st[r]);
            *(bf16x4*)&pb[wa[jt]] = pv4;
        }
    };
    auto back = [&](const bf16x8* bv) {
        const bf16x8 ap0 = *(const bf16x8*)&pb[ra0];
        const bf16x8 ap1 = *(const bf16x8*)&pb[ra1];
        lacc = __builtin_amdgcn_mfma_f32_16x16x32_bf16(ap0, ones, lacc, 0, 0, 0);
        lacc = __builtin_amdgcn_mfma_f32_16x16x32_bf16(ap1, ones, lacc, 0, 0, 0);
        o0 = __builtin_amdgcn_mfma_f32_16x16x32_bf16(ap0, bv[0], o0, 0, 0, 0);
        o0 = __builtin_amdgcn_mfma_f32_16x16x32_bf16(ap1, bv[1], o0, 0, 0, 0);
        o1 = __builtin_amdgcn_mfma_f32_16x16x32_bf16(ap0, bv[2], o1, 0, 0, 0);
        o1 = __builtin_amdgcn_mfma_f32_16x16x32_bf16(ap1, bv[3], o1, 0, 0, 0);
    };

    bf16x8 kf[2][4], vf[2][4];
    loadK(jbase, kf[0]);
    loadK(jbase + 64, kf[1]);
    front(kf[0], jbase, vf[0]);
    #pragma unroll
    for (int cc = 0; cc < 8; ++cc) {
        if (cc + 2 < 9) loadK(jbase + (cc + 2) * 64, kf[cc & 1]);
        back(vf[cc & 1]);                                     // reads P(cc)
        front(kf[(cc + 1) & 1], jbase + (cc + 1) * 64, vf[(cc + 1) & 1]); // writes P(cc+1)
    }
    back(vf[0]);   // chunk 8

    // ---- in-LDS split-K combine (l stored as column 32) ----
    __syncthreads();
    float* ob = (float*)smem;             // [4][16][33]; col32 = l
    #pragma unroll
    for (int r = 0; r < 4; ++r) {
        ob[(w4 * 16 + quad * 4 + r) * 33 + l16]      = o0[r];
        ob[(w4 * 16 + quad * 4 + r) * 33 + 16 + l16] = o1[r];
    }
    if (l16 == 0)
        #pragma unroll
        for (int r = 0; r < 4; ++r) ob[(w4 * 16 + quad * 4 + r) * 33 + 32] = lacc[r];
    __syncthreads();

    bf16* Ab = ws + 3 * QSZ + (size_t)bh * Nn * DH;
    for (int e = tid; e < 512; e += 256) {
        const int row = e >> 5, dd = e & 31;
        float os = ob[(row) * 33 + dd] + ob[(16 + row) * 33 + dd]
                 + ob[(32 + row) * 33 + dd] + ob[(48 + row) * 33 + dd];
        float lt = ob[(row) * 33 + 32] + ob[(16 + row) * 33 + 32]
                 + ob[(32 + row) * 33 + 32] + ob[(48 + row) * 33 + 32];
        Ab[(size_t)(i0 + row) * DH + dd] = (bf16)(os / lt);
    }
}

// ---------------- Kernel 3: output projection (z-split x8) -------------------
__global__ __launch_bounds__(256) void out_kernel(const bf16* __restrict__ wout,
                                                  const float* __restrict__ bout,
                                                  const bf16* __restrict__ Abuf,
                                                  float* __restrict__ out) {
    const int p0  = blockIdx.x * 64;
    const int b   = blockIdx.y;
    const int otb = blockIdx.z * 2;
    const int tid = threadIdx.x;
    const int lane = tid & 63, w4 = tid >> 6, l16 = lane & 15, quad = lane >> 4;
    const int p = p0 + w4 * 16 + l16;

    bf16x8 bfrag[4];
    #pragma unroll
    for (int h = 0; h < NH; ++h)
        bfrag[h] = *(const bf16x8*)&Abuf[((size_t)(b * NH + h) * Nn + p) * DH + quad * 8];

    #pragma unroll 1
    for (int oi = 0; oi < 2; ++oi) {
        const int ot = otb + oi;
        const int o0 = ot * 16;
        float4 b4 = *(const float4*)&bout[o0 + quad * 4];
        f32x4 acc0 = {b4.x, b4.y, b4.z, b4.w};
        f32x4 acc1 = {0.f, 0.f, 0.f, 0.f};
        #pragma unroll
        for (int kc = 0; kc < 2; ++kc) {
            bf16x8 aw0 = *(const bf16x8*)&wout[(((size_t)ot * 4 + kc) * 64 + lane) * 8];
            bf16x8 aw1 = *(const bf16x8*)&wout[(((size_t)ot * 4 + kc + 2) * 64 + lane) * 8];
            acc0 = __builtin_amdgcn_mfma_f32_16x16x32_bf16(aw0, bfrag[kc],     acc0, 0, 0, 0);
            acc1 = __builtin_amdgcn_mfma_f32_16x16x32_bf16(aw1, bfrag[kc + 2], acc1, 0, 0, 0);
        }
        #pragma unroll
        for (int r = 0; r < 4; ++r) {
            const int o = o0 + quad * 4 + r;
            out[((size_t)(b * Cdim + o)) * Nn + p] = acc0[r] + acc1[r];
        }
    }
}

extern "C" void kernel_launch(void* const* d_in, const int* in_sizes, int n_in,
                              void* d_out, int out_size, void* d_ws, size_t ws_size,
                              hipStream_t stream) {
    const float* x     = (const float*)d_in[0];
    const float* w_qkv = (const float*)d_in[1];
    const float* w_out = (const float*)d_in[2];
    const float* b_out = (const float*)d_in[3];
    bf16* ws   = (bf16*)d_ws;
    float* out = (float*)d_out;

    bf16* wq_bf = ws + 4 * QSZ;
    bf16* wo_bf = wq_bf + WQ_ELEMS;

    cvt_kernel <<<dim3(WQ_ELEMS / 256), 256, 0, stream>>>(w_qkv, w_out, wq_bf);
    qkv_kernel <<<dim3(36, Bn, 8), 256, 0, stream>>>(x, wq_bf, ws);
    attn_kernel<<<dim3(4608), 256, 0, stream>>>(ws);
    out_kernel <<<dim3(36, Bn, 8), 256, 0, stream>>>(wo_bf, b_out, ws + 3 * QSZ, out);
}